// Round 5
// baseline (435.544 us; speedup 1.0000x reference)
//
#include <hip/hip_runtime.h>
#include <hip/hip_bf16.h>

// ---------------------------------------------------------------------------
// GraphExpert: per-node expert MLPs (16 nodes, 2048 batch, 512 hid) + gating.
// fp32 global I/O, bf16 MFMA compute.
// R5: register-prefetch pipelined K-loops (plain loads, 2-barrier, single LDS
// buffer) in both GEMMs; gating GEMM fused into gemm1 (nblk==0 blocks) reusing
// the A fragments already in registers. Workspace stays in the proven 52.56 MB
// envelope.
// ---------------------------------------------------------------------------

typedef __attribute__((ext_vector_type(8))) short bf16x8;   // 8 bf16 = 4 VGPRs
typedef __attribute__((ext_vector_type(4))) float f32x4;    // MFMA C/D frag

// workspace layout (bytes) — identical to R2/R4 (proven safe)
#define OFF_W1T  (0u)          // bf16 [16][512][512]  (8 MB)
#define OFF_W2T  (8388608u)    // bf16 [16][512][512]  (8 MB)
#define OFF_H    (16777216u)   // bf16 [2048][16][512] (33.55 MB)
#define OFF_PART (50331648u)   // fp32 [16][2048][16]  (2 MB)
#define OFF_PROB (52428800u)   // fp32 [2048][16]      (128 KB)

// ------------- weight transpose + cvt: Wt[n][h][k] = bf16(W[n][k][h]) -------
__global__ void transpose_kernel(const float* __restrict__ W1,
                                 const float* __restrict__ W2,
                                 __hip_bfloat16* __restrict__ W1t,
                                 __hip_bfloat16* __restrict__ W2t) {
  __shared__ __hip_bfloat16 tile[32][33];
  const int n = blockIdx.z & 15;
  const float* src = (blockIdx.z >> 4) ? W2 : W1;
  __hip_bfloat16* dst = (blockIdx.z >> 4) ? W2t : W1t;
  src += (size_t)n * 262144;
  dst += (size_t)n * 262144;
  const int h0 = blockIdx.x * 32, k0 = blockIdx.y * 32;
  const int tx = threadIdx.x, ty = threadIdx.y; // 32 x 8
#pragma unroll
  for (int i = 0; i < 32; i += 8)
    tile[ty + i][tx] = __float2bfloat16(src[(size_t)(k0 + ty + i) * 512 + h0 + tx]);
  __syncthreads();
#pragma unroll
  for (int i = 0; i < 32; i += 8)
    dst[(size_t)(h0 + ty + i) * 512 + k0 + tx] = tile[tx][ty + i];
}

// ---------------- softmax: probs fp32 (ws) + expert_probs fp32 (out) --------
__global__ void softmax_kernel(const float* __restrict__ partial,
                               const float* __restrict__ bg,
                               float* __restrict__ probs,
                               float* __restrict__ probs_out) {
  const int r = blockIdx.x * 256 + threadIdx.x; // 0..2047
  float s[16];
#pragma unroll
  for (int j = 0; j < 16; j++) s[j] = 0.f;
  for (int nn = 0; nn < 16; nn++) {
    const float4* p = (const float4*)(partial + ((size_t)nn * 2048 + r) * 16);
#pragma unroll
    for (int c = 0; c < 4; c++) {
      float4 v = p[c];
      s[c * 4 + 0] += v.x; s[c * 4 + 1] += v.y;
      s[c * 4 + 2] += v.z; s[c * 4 + 3] += v.w;
    }
  }
  float mx = -1e30f;
#pragma unroll
  for (int j = 0; j < 16; j++) { s[j] += bg[j]; mx = fmaxf(mx, s[j]); }
  float sum = 0.f;
#pragma unroll
  for (int j = 0; j < 16; j++) { s[j] = __expf(s[j] - mx); sum += s[j]; }
  float inv = 1.f / sum;
#pragma unroll
  for (int j = 0; j < 16; j++) s[j] *= inv;
  float4* pw = (float4*)(probs + (size_t)r * 16);
  float4* ow = (float4*)(probs_out + (size_t)r * 16);
#pragma unroll
  for (int c = 0; c < 4; c++) {
    float4 v = make_float4(s[c*4], s[c*4+1], s[c*4+2], s[c*4+3]);
    pw[c] = v; ow[c] = v;
  }
}

// block-id remap: the 4 nblk siblings sharing one A-strip sit at bids
// b, b+8, b+16, b+24 (same bid%8 -> same XCD) for L2 reuse of the A strip.
__device__ __forceinline__ void decode_bid(int bid, int& nblk, int& mblk, int& n) {
  int x8 = bid & 7;
  nblk = (bid >> 3) & 3;
  int pair = (bid >> 5) * 8 + x8; // 0..255
  mblk = pair >> 4;
  n = pair & 15;
}

// ---------------- GEMM1 (+fused gating): h = bf16(relu(graphs@W1t + b1)) ----
// BK=64; XOR-swizzled LDS: LDS[row][slot s] = Gchunk[s ^ (row&7)] (16B chunks)
// Pipelined: tile ks+1 is loaded into VGPRs while MFMA of tile ks runs.
// nblk==0 blocks also compute gating partial[n][rows][16] = A @ WgT, reusing
// the av[] fragments already in registers.
__global__ __launch_bounds__(256, 3) void gemm1_kernel(
    const float* __restrict__ graphs,
    const __hip_bfloat16* __restrict__ W1t,
    const float* __restrict__ Wg,
    const float* __restrict__ b1,
    __hip_bfloat16* __restrict__ h,
    float* __restrict__ partial) {
  __shared__ char smem[36864]; // A 16K @0, B 16K @16384, WgT 16x144B @32768;
                               // epilogue reuses 4x9216
  const int tid = threadIdx.x, lane = tid & 63, wave = tid >> 6;
  int nblk, mblk, n;
  decode_bid(blockIdx.x, nblk, mblk, n);
  const int wm = (wave >> 1) * 64, wn = (wave & 1) * 64;
  const int q = lane >> 4, l15 = lane & 15;
  const int xr = l15 & 7;
  const int row2 = tid >> 1, half = tid & 1; // staging: row 0..127, 32-elem half
  const int rx = row2 & 7;
  const int wk = tid >> 2, wj = (tid & 3) * 4; // Wg staging: k 0..63, j group
  const bool do_gate = (nblk == 0);
  const int gt0 = (wave & 1) * 2; // gating uses av[gt0], av[gt0+1]

  const float* Ag = graphs + (size_t)(mblk * 128) * 8192 + n * 512;
  const __hip_bfloat16* Bg = W1t + (size_t)n * 262144 + (size_t)(nblk * 128) * 512;
  const float* Wgg = Wg + (size_t)(n * 512) * 16;

  const float* asrc = Ag + (size_t)row2 * 8192 + half * 32;
  const __hip_bfloat16* bsrc = Bg + (size_t)row2 * 512 + half * 32;

  float af[32];
  uint4 bq[4];
  float4 wgq = make_float4(0.f, 0.f, 0.f, 0.f);
  // prologue: load tile ks=0
#pragma unroll
  for (int j = 0; j < 8; j++) *(float4*)(af + j * 4) = *(const float4*)(asrc + j * 4);
#pragma unroll
  for (int j = 0; j < 4; j++) bq[j] = ((const uint4*)bsrc)[j];
  if (do_gate) wgq = *(const float4*)(Wgg + (size_t)wk * 16 + wj);

  f32x4 acc[4][4] = {};
  f32x4 accg[2] = {};
  for (int ks = 0; ks < 8; ks++) {
    // ---- stage tile ks from regs into LDS (swizzled)
    __hip_bfloat16 t[32];
#pragma unroll
    for (int e = 0; e < 32; e++) t[e] = __float2bfloat16(af[e]);
    char* abase = smem + row2 * 128;
    char* bbase = smem + 16384 + row2 * 128;
#pragma unroll
    for (int j = 0; j < 4; j++) {
      int c = half * 4 + j;
      *(bf16x8*)(abase + ((c ^ rx) * 16)) = *(const bf16x8*)(t + j * 8);
      *(uint4*)(bbase + ((c ^ rx) * 16)) = bq[j];
    }
    if (do_gate) {
      __hip_bfloat16 wt[4] = {__float2bfloat16(wgq.x), __float2bfloat16(wgq.y),
                              __float2bfloat16(wgq.z), __float2bfloat16(wgq.w)};
#pragma unroll
      for (int i = 0; i < 4; i++)
        *(__hip_bfloat16*)(smem + 32768 + (wj + i) * 144 + wk * 2) = wt[i];
    }
    __syncthreads();
    // ---- issue prefetch for tile ks+1 (latency hidden behind MFMA phase)
    if (ks < 7) {
      const int kp = (ks + 1) * 64;
#pragma unroll
      for (int j = 0; j < 8; j++)
        *(float4*)(af + j * 4) = *(const float4*)(asrc + kp + j * 4);
#pragma unroll
      for (int j = 0; j < 4; j++) bq[j] = ((const uint4*)(bsrc + kp))[j];
      if (do_gate) wgq = *(const float4*)(Wgg + (size_t)(kp + wk) * 16 + wj);
    }
    // ---- MFMA phase for tile ks
#pragma unroll
    for (int hh = 0; hh < 2; hh++) {
      const int co = ((q + hh * 4) ^ xr) * 16;
      bf16x8 av[4], bv[4];
#pragma unroll
      for (int im = 0; im < 4; im++)
        av[im] = *(const bf16x8*)(smem + (wm + im * 16 + l15) * 128 + co);
#pragma unroll
      for (int in = 0; in < 4; in++)
        bv[in] = *(const bf16x8*)(smem + 16384 + (wn + in * 16 + l15) * 128 + co);
#pragma unroll
      for (int im = 0; im < 4; im++)
#pragma unroll
        for (int in = 0; in < 4; in++)
          acc[im][in] = __builtin_amdgcn_mfma_f32_16x16x32_bf16(av[im], bv[in], acc[im][in], 0, 0, 0);
      if (do_gate) {
        bf16x8 wv = *(const bf16x8*)(smem + 32768 + l15 * 144 + (q + hh * 4) * 16);
        accg[0] = __builtin_amdgcn_mfma_f32_16x16x32_bf16(av[gt0], wv, accg[0], 0, 0, 0);
        accg[1] = __builtin_amdgcn_mfma_f32_16x16x32_bf16(av[gt0 + 1], wv, accg[1], 0, 0, 0);
      }
    }
    __syncthreads();
  }

  // ---- gating epilogue: partial[n][row][j]
  if (do_gate) {
#pragma unroll
    for (int t2 = 0; t2 < 2; t2++)
#pragma unroll
      for (int r = 0; r < 4; r++) {
        int row = mblk * 128 + wave * 32 + t2 * 16 + q * 4 + r;
        partial[((size_t)n * 2048 + row) * 16 + l15] = accg[t2][r];
      }
  }

  // ---- main epilogue: bias+relu, repack via LDS (stride 144 B), coalesced store
  float bias[4];
#pragma unroll
  for (int in = 0; in < 4; in++)
    bias[in] = b1[n * 512 + nblk * 128 + wn + in * 16 + l15];
  char* epi = smem + wave * 9216;
#pragma unroll
  for (int im = 0; im < 4; im++)
#pragma unroll
    for (int in = 0; in < 4; in++)
#pragma unroll
      for (int r = 0; r < 4; r++) {
        float v = acc[im][in][r] + bias[in];
        v = fmaxf(v, 0.f);
        int rl = im * 16 + q * 4 + r;
        int cl = in * 16 + l15;
        *(__hip_bfloat16*)(epi + rl * 144 + cl * 2) = __float2bfloat16(v);
      }
  __syncthreads();
  __hip_bfloat16* Hg = h + (size_t)(mblk * 128 + wm) * 8192 + n * 512 + nblk * 128 + wn;
#pragma unroll
  for (int it = 0; it < 8; it++) {
    int rl = it * 8 + (lane >> 3);
    int cl = (lane & 7) * 8;
    bf16x8 v = *(const bf16x8*)(epi + rl * 144 + cl * 2);
    *(bf16x8*)(Hg + (size_t)rl * 8192 + cl) = v;
  }
}

// ---------------- GEMM2 + weighted combine (fp32 out), pipelined ------------
__global__ __launch_bounds__(256, 3) void gemm2_kernel(
    const __hip_bfloat16* __restrict__ hbuf,
    const __hip_bfloat16* __restrict__ W2t,
    const float* __restrict__ b2,
    const float* __restrict__ probs,
    float* __restrict__ out) {
  __shared__ char smem[32768];
  const int tid = threadIdx.x, lane = tid & 63, wave = tid >> 6;
  int nblk, mblk, n;
  decode_bid(blockIdx.x, nblk, mblk, n);
  const int wm = (wave >> 1) * 64, wn = (wave & 1) * 64;
  const int q = lane >> 4, l15 = lane & 15;
  const int xr = l15 & 7;
  const int row2 = tid >> 1, half = tid & 1;
  const int rx = row2 & 7;

  const __hip_bfloat16* Ag = hbuf + (size_t)(mblk * 128) * 8192 + n * 512;
  const __hip_bfloat16* Bg = W2t + (size_t)n * 262144 + (size_t)(nblk * 128) * 512;
  const __hip_bfloat16* asrc = Ag + (size_t)row2 * 8192 + half * 32;
  const __hip_bfloat16* bsrc = Bg + (size_t)row2 * 512 + half * 32;

  uint4 aq[4], bq[4];
#pragma unroll
  for (int j = 0; j < 4; j++) {
    aq[j] = ((const uint4*)asrc)[j];
    bq[j] = ((const uint4*)bsrc)[j];
  }

  f32x4 acc[4][4] = {};
  for (int ks = 0; ks < 8; ks++) {
    char* abase = smem + row2 * 128;
    char* bbase = smem + 16384 + row2 * 128;
#pragma unroll
    for (int j = 0; j < 4; j++) {
      int c = half * 4 + j;
      *(uint4*)(abase + ((c ^ rx) * 16)) = aq[j];
      *(uint4*)(bbase + ((c ^ rx) * 16)) = bq[j];
    }
    __syncthreads();
    if (ks < 7) {
      const int kp = (ks + 1) * 64;
#pragma unroll
      for (int j = 0; j < 4; j++) {
        aq[j] = ((const uint4*)(asrc + kp))[j];
        bq[j] = ((const uint4*)(bsrc + kp))[j];
      }
    }
#pragma unroll
    for (int hh = 0; hh < 2; hh++) {
      const int co = ((q + hh * 4) ^ xr) * 16;
      bf16x8 av[4], bv[4];
#pragma unroll
      for (int im = 0; im < 4; im++)
        av[im] = *(const bf16x8*)(smem + (wm + im * 16 + l15) * 128 + co);
#pragma unroll
      for (int in = 0; in < 4; in++)
        bv[in] = *(const bf16x8*)(smem + 16384 + (wn + in * 16 + l15) * 128 + co);
#pragma unroll
      for (int im = 0; im < 4; im++)
#pragma unroll
        for (int in = 0; in < 4; in++)
          acc[im][in] = __builtin_amdgcn_mfma_f32_16x16x32_bf16(av[im], bv[in], acc[im][in], 0, 0, 0);
    }
    __syncthreads();
  }

  // epilogue: (outs + b2) * probs, shfl-reduce over the 16 j-cols,
  // combined[b, 32n + nblk*8 + (wn>>4) + in]
  float bias[4];
#pragma unroll
  for (int in = 0; in < 4; in++)
    bias[in] = b2[n * 512 + nblk * 128 + wn + in * 16 + l15];
  float* comb = (float*)smem; // [128][8] fp32 (staging LDS reused)
#pragma unroll
  for (int im = 0; im < 4; im++)
#pragma unroll
    for (int r = 0; r < 4; r++) {
      int rl = wm + im * 16 + q * 4 + r; // block-local row 0..127
      float pv = probs[(size_t)(mblk * 128 + rl) * 16 + l15];
#pragma unroll
      for (int in = 0; in < 4; in++) {
        float v = (acc[im][in][r] + bias[in]) * pv;
        v += __shfl_xor(v, 1);
        v += __shfl_xor(v, 2);
        v += __shfl_xor(v, 4);
        v += __shfl_xor(v, 8);
        if (l15 == 0) comb[rl * 8 + (wn >> 4) + in] = v;
      }
    }
  __syncthreads();
  if (tid < 128) {
    float4 v0 = *(const float4*)(comb + tid * 8);
    float4 v1 = *(const float4*)(comb + tid * 8 + 4);
    float* orow = out + (size_t)(mblk * 128 + tid) * 512 + n * 32 + nblk * 8;
    *(float4*)orow = v0;
    *(float4*)(orow + 4) = v1;
  }
}

// ---------------------------------------------------------------------------
extern "C" void kernel_launch(void* const* d_in, const int* in_sizes, int n_in,
                              void* d_out, int out_size, void* d_ws, size_t ws_size,
                              hipStream_t stream) {
  const float* graphs = (const float*)d_in[0];
  const float* W1 = (const float*)d_in[1];
  const float* b1 = (const float*)d_in[2];
  const float* W2 = (const float*)d_in[3];
  const float* b2 = (const float*)d_in[4];
  const float* Wg = (const float*)d_in[5];
  const float* bg = (const float*)d_in[6];
  float* out = (float*)d_out;

  char* ws = (char*)d_ws;
  __hip_bfloat16* W1t = (__hip_bfloat16*)(ws + OFF_W1T);
  __hip_bfloat16* W2t = (__hip_bfloat16*)(ws + OFF_W2T);
  __hip_bfloat16* hb  = (__hip_bfloat16*)(ws + OFF_H);
  float* partial = (float*)(ws + OFF_PART);
  float* probs   = (float*)(ws + OFF_PROB);

  transpose_kernel<<<dim3(16, 16, 32), dim3(32, 8), 0, stream>>>(W1, W2, W1t, W2t);
  gemm1_kernel<<<1024, 256, 0, stream>>>(graphs, W1t, Wg, b1, hb, partial);
  softmax_kernel<<<8, 256, 0, stream>>>(partial, bg, probs, out + 2048 * 512);
  gemm2_kernel<<<1024, 256, 0, stream>>>(hb, W2t, b2, probs, out);
}

// Round 6
// 327.971 us; speedup vs baseline: 1.3280x; 1.3280x over previous
//
#include <hip/hip_runtime.h>
#include <hip/hip_bf16.h>

// ---------------------------------------------------------------------------
// GraphExpert: per-node expert MLPs (16 nodes, 2048 batch, 512 hid) + gating.
// fp32 global I/O, bf16 MFMA compute.
// R6: gemm1 = m97-style 2-barrier loop, BOTH operands via global_load_lds
// (A staged as raw fp32, cvt at fragment-read time -> zero staging VGPRs, no
// spill); fused gating kept (R5-proven). gemm2 reverted to R4-proven version.
// Workspace stays in the proven 52.56 MB envelope.
// ---------------------------------------------------------------------------

typedef __attribute__((ext_vector_type(8))) short bf16x8;   // 8 bf16 = 4 VGPRs
typedef __attribute__((ext_vector_type(4))) float f32x4;    // MFMA C/D frag

// workspace layout (bytes) — identical to R2/R4 (proven safe)
#define OFF_W1T  (0u)          // bf16 [16][512][512]  (8 MB)
#define OFF_W2T  (8388608u)    // bf16 [16][512][512]  (8 MB)
#define OFF_H    (16777216u)   // bf16 [2048][16][512] (33.55 MB)
#define OFF_PART (50331648u)   // fp32 [16][2048][16]  (2 MB)
#define OFF_PROB (52428800u)   // fp32 [2048][16]      (128 KB)

__device__ __forceinline__ void gl2lds16(const void* g, void* l) {
  __builtin_amdgcn_global_load_lds(
      (const __attribute__((address_space(1))) void*)g,
      (__attribute__((address_space(3))) void*)l, 16, 0, 0);
}

// ------------- weight transpose + cvt: Wt[n][h][k] = bf16(W[n][k][h]) -------
__global__ void transpose_kernel(const float* __restrict__ W1,
                                 const float* __restrict__ W2,
                                 __hip_bfloat16* __restrict__ W1t,
                                 __hip_bfloat16* __restrict__ W2t) {
  __shared__ __hip_bfloat16 tile[32][33];
  const int n = blockIdx.z & 15;
  const float* src = (blockIdx.z >> 4) ? W2 : W1;
  __hip_bfloat16* dst = (blockIdx.z >> 4) ? W2t : W1t;
  src += (size_t)n * 262144;
  dst += (size_t)n * 262144;
  const int h0 = blockIdx.x * 32, k0 = blockIdx.y * 32;
  const int tx = threadIdx.x, ty = threadIdx.y; // 32 x 8
#pragma unroll
  for (int i = 0; i < 32; i += 8)
    tile[ty + i][tx] = __float2bfloat16(src[(size_t)(k0 + ty + i) * 512 + h0 + tx]);
  __syncthreads();
#pragma unroll
  for (int i = 0; i < 32; i += 8)
    dst[(size_t)(h0 + ty + i) * 512 + k0 + tx] = tile[tx][ty + i];
}

// ---------------- softmax: probs fp32 (ws) + expert_probs fp32 (out) --------
__global__ void softmax_kernel(const float* __restrict__ partial,
                               const float* __restrict__ bg,
                               float* __restrict__ probs,
                               float* __restrict__ probs_out) {
  const int r = blockIdx.x * 256 + threadIdx.x; // 0..2047
  float s[16];
#pragma unroll
  for (int j = 0; j < 16; j++) s[j] = 0.f;
  for (int nn = 0; nn < 16; nn++) {
    const float4* p = (const float4*)(partial + ((size_t)nn * 2048 + r) * 16);
#pragma unroll
    for (int c = 0; c < 4; c++) {
      float4 v = p[c];
      s[c * 4 + 0] += v.x; s[c * 4 + 1] += v.y;
      s[c * 4 + 2] += v.z; s[c * 4 + 3] += v.w;
    }
  }
  float mx = -1e30f;
#pragma unroll
  for (int j = 0; j < 16; j++) { s[j] += bg[j]; mx = fmaxf(mx, s[j]); }
  float sum = 0.f;
#pragma unroll
  for (int j = 0; j < 16; j++) { s[j] = __expf(s[j] - mx); sum += s[j]; }
  float inv = 1.f / sum;
#pragma unroll
  for (int j = 0; j < 16; j++) s[j] *= inv;
  float4* pw = (float4*)(probs + (size_t)r * 16);
  float4* ow = (float4*)(probs_out + (size_t)r * 16);
#pragma unroll
  for (int c = 0; c < 4; c++) {
    float4 v = make_float4(s[c*4], s[c*4+1], s[c*4+2], s[c*4+3]);
    pw[c] = v; ow[c] = v;
  }
}

// block-id remap: the 4 nblk siblings sharing one A-strip sit at bids
// b, b+8, b+16, b+24 (same bid%8 -> same XCD) for L2 reuse of the A strip.
__device__ __forceinline__ void decode_bid(int bid, int& nblk, int& mblk, int& n) {
  int x8 = bid & 7;
  nblk = (bid >> 3) & 3;
  int pair = (bid >> 5) * 8 + x8; // 0..255
  mblk = pair >> 4;
  n = pair & 15;
}

// ---------------- GEMM1 (+fused gating): h = bf16(relu(graphs@W1t + b1)) ----
// LDS: A fp32 [128 rows][16 chunks16B] swizzled @0 (32K);
//      B bf16 [128 rows][8 chunks16B] swizzled @32768 (16K);
//      WgT bf16 [16][64] stride 144B @49152 (2304 B).
// Invariants: A: LDS[r][s] = Gchunk[s ^ (r&15)]; B: LDS[r][s] = G[s ^ (r&7)].
// Both operands via global_load_lds (zero staging VGPRs). fp32->bf16 cvt at
// fragment-read time. nblk==0 blocks also accumulate gating partials (R5-
// proven fragment reuse).
__global__ __launch_bounds__(256, 3) void gemm1_kernel(
    const float* __restrict__ graphs,
    const __hip_bfloat16* __restrict__ W1t,
    const float* __restrict__ Wg,
    const float* __restrict__ b1,
    __hip_bfloat16* __restrict__ h,
    float* __restrict__ partial) {
  __shared__ char smem[51456];
  const int tid = threadIdx.x, lane = tid & 63, wave = tid >> 6;
  int nblk, mblk, n;
  decode_bid(blockIdx.x, nblk, mblk, n);
  const int wm = (wave >> 1) * 64, wn = (wave & 1) * 64;
  const int q = lane >> 4, l15 = lane & 15;
  // A staging (fp32, 16 chunks/row): 4 rows per issue
  const int a_r = lane >> 4;            // 0..3 row within issue
  const int a_s = lane & 15;            // LDS slot
  // B staging (bf16, 8 chunks/row): 8 rows per issue
  const int b_r = lane >> 3, b_s = lane & 7;
  // Wg staging
  const int wk = tid >> 2, wj = (tid & 3) * 4;
  const bool do_gate = (nblk == 0);
  const int gt0 = (wave & 1) * 2;

  const float* Ag = graphs + (size_t)(mblk * 128) * 8192 + n * 512;
  const __hip_bfloat16* Bg = W1t + (size_t)n * 262144 + (size_t)(nblk * 128) * 512;
  const float* Wgg = Wg + (size_t)(n * 512) * 16;

  f32x4 acc[4][4] = {};
  f32x4 accg[2] = {};
  for (int ks = 0; ks < 8; ks++) {
    const int k0 = ks * 64; // fp32 elements
    // ---- A: 8 issues/wave, rows w*32+i*4 .. +3, global chunk = s ^ (r&15)
#pragma unroll
    for (int i = 0; i < 8; i++) {
      const int r = wave * 32 + i * 4 + a_r;
      const int g = a_s ^ (r & 15);
      gl2lds16(Ag + (size_t)r * 8192 + k0 + g * 4,
               smem + r * 256 + a_s * 16);
    }
    // ---- B: 4 issues/wave, rows i*32+w*8 .. +7, global chunk = s ^ (r&7)
#pragma unroll
    for (int i = 0; i < 4; i++) {
      const int r = i * 32 + wave * 8 + b_r;
      const int g = b_s ^ (r & 7);
      gl2lds16(Bg + (size_t)r * 512 + k0 + g * 8,
               smem + 32768 + r * 128 + b_s * 16);
    }
    // ---- WgT slice for this k-chunk (gating blocks only)
    if (do_gate) {
      float4 wgq = *(const float4*)(Wgg + (size_t)(k0 + wk) * 16 + wj);
      __hip_bfloat16 wt[4] = {__float2bfloat16(wgq.x), __float2bfloat16(wgq.y),
                              __float2bfloat16(wgq.z), __float2bfloat16(wgq.w)};
#pragma unroll
      for (int i = 0; i < 4; i++)
        *(__hip_bfloat16*)(smem + 49152 + (wj + i) * 144 + wk * 2) = wt[i];
    }
    __syncthreads();
    // ---- MFMA phase
#pragma unroll
    for (int hh = 0; hh < 2; hh++) {
      const int c0 = (q + hh * 4) * 2; // first fp32 chunk of this k-octet
      bf16x8 av[4], bv[4];
#pragma unroll
      for (int im = 0; im < 4; im++) {
        const int m = wm + im * 16 + l15;
        float4 f0 = *(const float4*)(smem + m * 256 + ((c0 ^ l15) * 16));
        float4 f1 = *(const float4*)(smem + m * 256 + (((c0 + 1) ^ l15) * 16));
        __hip_bfloat16 t[8] = {
            __float2bfloat16(f0.x), __float2bfloat16(f0.y),
            __float2bfloat16(f0.z), __float2bfloat16(f0.w),
            __float2bfloat16(f1.x), __float2bfloat16(f1.y),
            __float2bfloat16(f1.z), __float2bfloat16(f1.w)};
        av[im] = *(const bf16x8*)t;
      }
#pragma unroll
      for (int in = 0; in < 4; in++) {
        const int rr = wn + in * 16 + l15;
        bv[in] = *(const bf16x8*)(smem + 32768 + rr * 128 +
                                  (((q + hh * 4) ^ (l15 & 7)) * 16));
      }
#pragma unroll
      for (int im = 0; im < 4; im++)
#pragma unroll
        for (int in = 0; in < 4; in++)
          acc[im][in] = __builtin_amdgcn_mfma_f32_16x16x32_bf16(av[im], bv[in], acc[im][in], 0, 0, 0);
      if (do_gate) {
        bf16x8 wv = *(const bf16x8*)(smem + 49152 + l15 * 144 + (q + hh * 4) * 16);
        accg[0] = __builtin_amdgcn_mfma_f32_16x16x32_bf16(av[gt0], wv, accg[0], 0, 0, 0);
        accg[1] = __builtin_amdgcn_mfma_f32_16x16x32_bf16(av[gt0 + 1], wv, accg[1], 0, 0, 0);
      }
    }
    __syncthreads();
  }

  // ---- gating epilogue: partial[n][row][j]  (R5-proven)
  if (do_gate) {
#pragma unroll
    for (int t2 = 0; t2 < 2; t2++)
#pragma unroll
      for (int r = 0; r < 4; r++) {
        int row = mblk * 128 + wave * 32 + t2 * 16 + q * 4 + r;
        partial[((size_t)n * 2048 + row) * 16 + l15] = accg[t2][r];
      }
  }

  // ---- main epilogue: bias+relu, repack via LDS (stride 144 B), coalesced store
  float bias[4];
#pragma unroll
  for (int in = 0; in < 4; in++)
    bias[in] = b1[n * 512 + nblk * 128 + wn + in * 16 + l15];
  char* epi = smem + wave * 9216;
#pragma unroll
  for (int im = 0; im < 4; im++)
#pragma unroll
    for (int in = 0; in < 4; in++)
#pragma unroll
      for (int r = 0; r < 4; r++) {
        float v = acc[im][in][r] + bias[in];
        v = fmaxf(v, 0.f);
        int rl = im * 16 + q * 4 + r;
        int cl = in * 16 + l15;
        *(__hip_bfloat16*)(epi + rl * 144 + cl * 2) = __float2bfloat16(v);
      }
  __syncthreads();
  __hip_bfloat16* Hg = h + (size_t)(mblk * 128 + wm) * 8192 + n * 512 + nblk * 128 + wn;
#pragma unroll
  for (int it = 0; it < 8; it++) {
    int rl = it * 8 + (lane >> 3);
    int cl = (lane & 7) * 8;
    bf16x8 v = *(const bf16x8*)(epi + rl * 144 + cl * 2);
    *(bf16x8*)(Hg + (size_t)rl * 8192 + cl) = v;
  }
}

// ---------------- GEMM2 + weighted combine (fp32 out) — R4-proven -----------
__global__ __launch_bounds__(256, 4) void gemm2_kernel(
    const __hip_bfloat16* __restrict__ hbuf,
    const __hip_bfloat16* __restrict__ W2t,
    const float* __restrict__ b2,
    const float* __restrict__ probs,
    float* __restrict__ out) {
  __shared__ char smem[32768];
  const int tid = threadIdx.x, lane = tid & 63, wave = tid >> 6;
  int nblk, mblk, n;
  decode_bid(blockIdx.x, nblk, mblk, n);
  const int wm = (wave >> 1) * 64, wn = (wave & 1) * 64;
  const int q = lane >> 4, l15 = lane & 15;
  const int lrow = lane >> 3, lcol = lane & 7;
  const int swz = (lcol ^ lrow) * 8;
  const int xr = l15 & 7;

  const __hip_bfloat16* Ag = hbuf + (size_t)(mblk * 128) * 8192 + n * 512;
  const __hip_bfloat16* Bg = W2t + (size_t)n * 262144 + (size_t)(nblk * 128) * 512;

  f32x4 acc[4][4] = {};
  for (int ks = 0; ks < 8; ks++) {
    const int k0 = ks * 64;
#pragma unroll
    for (int i = 0; i < 4; i++) {
      const int r = i * 32 + wave * 8 + lrow;
      gl2lds16(Ag + (size_t)r * 8192 + k0 + swz, smem + i * 4096 + wave * 1024 + lane * 16);
      gl2lds16(Bg + (size_t)r * 512 + k0 + swz,
               smem + 16384 + i * 4096 + wave * 1024 + lane * 16);
    }
    __syncthreads();
#pragma unroll
    for (int hh = 0; hh < 2; hh++) {
      const int co = ((q + hh * 4) ^ xr) * 16;
      bf16x8 av[4], bv[4];
#pragma unroll
      for (int im = 0; im < 4; im++)
        av[im] = *(const bf16x8*)(smem + (wm + im * 16 + l15) * 128 + co);
#pragma unroll
      for (int in = 0; in < 4; in++)
        bv[in] = *(const bf16x8*)(smem + 16384 + (wn + in * 16 + l15) * 128 + co);
#pragma unroll
      for (int im = 0; im < 4; im++)
#pragma unroll
        for (int in = 0; in < 4; in++)
          acc[im][in] = __builtin_amdgcn_mfma_f32_16x16x32_bf16(av[im], bv[in], acc[im][in], 0, 0, 0);
    }
    __syncthreads();
  }

  float bias[4];
#pragma unroll
  for (int in = 0; in < 4; in++)
    bias[in] = b2[n * 512 + nblk * 128 + wn + in * 16 + l15];
  float* comb = (float*)smem; // [128][8] fp32 (staging LDS reused)
#pragma unroll
  for (int im = 0; im < 4; im++)
#pragma unroll
    for (int r = 0; r < 4; r++) {
      int rl = wm + im * 16 + q * 4 + r; // block-local row 0..127
      float pv = probs[(size_t)(mblk * 128 + rl) * 16 + l15];
#pragma unroll
      for (int in = 0; in < 4; in++) {
        float v = (acc[im][in][r] + bias[in]) * pv;
        v += __shfl_xor(v, 1);
        v += __shfl_xor(v, 2);
        v += __shfl_xor(v, 4);
        v += __shfl_xor(v, 8);
        if (l15 == 0) comb[rl * 8 + (wn >> 4) + in] = v;
      }
    }
  __syncthreads();
  if (tid < 128) {
    float4 v0 = *(const float4*)(comb + tid * 8);
    float4 v1 = *(const float4*)(comb + tid * 8 + 4);
    float* orow = out + (size_t)(mblk * 128 + tid) * 512 + n * 32 + nblk * 8;
    *(float4*)orow = v0;
    *(float4*)(orow + 4) = v1;
  }
}

// ---------------------------------------------------------------------------
extern "C" void kernel_launch(void* const* d_in, const int* in_sizes, int n_in,
                              void* d_out, int out_size, void* d_ws, size_t ws_size,
                              hipStream_t stream) {
  const float* graphs = (const float*)d_in[0];
  const float* W1 = (const float*)d_in[1];
  const float* b1 = (const float*)d_in[2];
  const float* W2 = (const float*)d_in[3];
  const float* b2 = (const float*)d_in[4];
  const float* Wg = (const float*)d_in[5];
  const float* bg = (const float*)d_in[6];
  float* out = (float*)d_out;

  char* ws = (char*)d_ws;
  __hip_bfloat16* W1t = (__hip_bfloat16*)(ws + OFF_W1T);
  __hip_bfloat16* W2t = (__hip_bfloat16*)(ws + OFF_W2T);
  __hip_bfloat16* hb  = (__hip_bfloat16*)(ws + OFF_H);
  float* partial = (float*)(ws + OFF_PART);
  float* probs   = (float*)(ws + OFF_PROB);

  transpose_kernel<<<dim3(16, 16, 32), dim3(32, 8), 0, stream>>>(W1, W2, W1t, W2t);
  gemm1_kernel<<<1024, 256, 0, stream>>>(graphs, W1t, Wg, b1, hb, partial);
  softmax_kernel<<<8, 256, 0, stream>>>(partial, bg, probs, out + 2048 * 512);
  gemm2_kernel<<<1024, 256, 0, stream>>>(hb, W2t, b2, probs, out);
}